// Round 7
// baseline (261.982 us; speedup 1.0000x reference)
//
#include <hip/hip_runtime.h>

#define B_  8
#define C_  256
#define N_  16384
#define NM_ 128

typedef _Float16 f16x8 __attribute__((ext_vector_type(8)));
typedef float    f32x4 __attribute__((ext_vector_type(4)));

// ---------------- kernel 1: split-K fp16x2 MFMA GEMM, fp32-in-LDS via global_load_lds ----------------
// 512 threads (8 waves), 128x128 tile, KB=32 fp32 staged by DMA (no VGPR round-trip).
// LDS linear [128][32] fp32; XOR swizzle (16B unit ^= row&7) applied on BOTH the global source
// address and the ds_read side (rule #21). hi/lo f16 conversion fused into the consume phase.
__global__ __launch_bounds__(512)
__attribute__((amdgpu_waves_per_eu(4, 4)))
void gemm_f16_kernel(const float* __restrict__ X,
                     const float* __restrict__ Y,
                     float* __restrict__ Gp,
                     float* __restrict__ x2p,
                     float* __restrict__ y2p,
                     int Kchunk) {
    __shared__ float A_lds[2][128 * 32];
    __shared__ float B_lds[2][128 * 32];

    int lin = blockIdx.x;
    int jt = lin & 1, it = (lin >> 1) & 1, b = (lin >> 2) & 7, ks = lin >> 5;
    int k0 = ks * Kchunk;

    int t = threadIdx.x;
    int lane = t & 63;
    int wid = t >> 6;                 // 8 waves
    int wm = wid >> 1, wn = wid & 1;  // wave tile: rows wm*32.., cols wn*64..

    const float* Xb = X + ((size_t)(b * C_) + it * 128) * N_;
    const float* Yb = Y + ((size_t)(b * C_) + jt * 128) * N_;

    // per-lane staging geometry: wave wid covers tile rows [wid*16, wid*16+16) in 2 DMA ops
    int srow_lane = lane >> 3;               // 0..7 (row within 8-row group)
    int sunit = (lane & 7) ^ srow_lane;      // pre-swizzled 16B unit within the 128B row segment

    f32x4 acc[2][4] = {};
    float sA[2] = {0.f, 0.f};
    float sB[4] = {0.f, 0.f, 0.f, 0.f};

    auto stage = [&](int bi, int kk) {
#pragma unroll
        for (int q = 0; q < 2; ++q) {
            int rowt = wid * 16 + q * 8 + srow_lane;                      // per-lane tile row
            const float* ga = Xb + (size_t)rowt * N_ + k0 + kk + sunit * 4;
            const float* gb = Yb + (size_t)rowt * N_ + k0 + kk + sunit * 4;
            __builtin_amdgcn_global_load_lds(
                (const __attribute__((address_space(1))) void*)ga,
                (__attribute__((address_space(3))) void*)&A_lds[bi][(wid * 16 + q * 8) * 32],
                16, 0, 0);
            __builtin_amdgcn_global_load_lds(
                (const __attribute__((address_space(1))) void*)gb,
                (__attribute__((address_space(3))) void*)&B_lds[bi][(wid * 16 + q * 8) * 32],
                16, 0, 0);
        }
    };

// convert 8 staged fp32 (two f32x4) into hi/lo f16x8, accumulating squared-norm
#define CVT(P0, P1, HI, LO, SQ)                           \
    {                                                     \
        float tmp_[8];                                    \
        *(f32x4*)&tmp_[0] = (P0);                         \
        *(f32x4*)&tmp_[4] = (P1);                         \
        _Pragma("unroll")                                 \
        for (int e_ = 0; e_ < 8; ++e_) {                  \
            float v_ = tmp_[e_];                          \
            _Float16 h_ = (_Float16)v_;                   \
            (HI)[e_] = h_;                                \
            (LO)[e_] = (_Float16)(v_ - (float)h_);        \
            (SQ) += v_ * v_;                              \
        }                                                 \
    }

#define MFMA16(A, Bf, Cc) __builtin_amdgcn_mfma_f32_16x16x32_f16((A), (Bf), (Cc), 0, 0, 0)

// one K-step: issue next chunk's DMA, ds_read+convert fragments from buf RD, MFMA,
// then drain own DMA (vmcnt 0) + barrier. Loads fly during the whole convert+MFMA phase.
#define KSTEP(RD, WR, KOFF)                                                            \
    {                                                                                  \
        if ((KOFF) + 32 < Kchunk) stage(WR, (KOFF) + 32);                              \
        f16x8 aHi[2], aLo[2], bHi[4], bLo[4];                                          \
        _Pragma("unroll")                                                              \
        for (int mf = 0; mf < 2; ++mf) {                                               \
            int rl = wm * 32 + mf * 16 + (lane & 15);                                  \
            int s7 = rl & 7, g2 = (lane >> 4) * 2;                                     \
            f32x4 p0 = *(const f32x4*)&A_lds[RD][rl * 32 + (g2 ^ s7) * 4];             \
            f32x4 p1 = *(const f32x4*)&A_lds[RD][rl * 32 + ((g2 + 1) ^ s7) * 4];       \
            CVT(p0, p1, aHi[mf], aLo[mf], sA[mf]);                                     \
        }                                                                              \
        _Pragma("unroll")                                                              \
        for (int nf = 0; nf < 4; ++nf) {                                               \
            int rl = wn * 64 + nf * 16 + (lane & 15);                                  \
            int s7 = rl & 7, g2 = (lane >> 4) * 2;                                     \
            f32x4 p0 = *(const f32x4*)&B_lds[RD][rl * 32 + (g2 ^ s7) * 4];             \
            f32x4 p1 = *(const f32x4*)&B_lds[RD][rl * 32 + ((g2 + 1) ^ s7) * 4];       \
            CVT(p0, p1, bHi[nf], bLo[nf], sB[nf]);                                     \
        }                                                                              \
        __builtin_amdgcn_s_setprio(1);                                                 \
        _Pragma("unroll")                                                              \
        for (int nf = 0; nf < 4; ++nf) {                                               \
            acc[0][nf] = MFMA16(aHi[0], bHi[nf], acc[0][nf]);                          \
            acc[1][nf] = MFMA16(aHi[1], bHi[nf], acc[1][nf]);                          \
            acc[0][nf] = MFMA16(aHi[0], bLo[nf], acc[0][nf]);                          \
            acc[1][nf] = MFMA16(aHi[1], bLo[nf], acc[1][nf]);                          \
            acc[0][nf] = MFMA16(aLo[0], bHi[nf], acc[0][nf]);                          \
            acc[1][nf] = MFMA16(aLo[1], bHi[nf], acc[1][nf]);                          \
        }                                                                              \
        __builtin_amdgcn_s_setprio(0);                                                 \
        asm volatile("s_waitcnt vmcnt(0)" ::: "memory");                               \
        __builtin_amdgcn_s_barrier();                                                  \
        __builtin_amdgcn_sched_barrier(0);                                             \
    }

    // prologue: DMA chunk 0 into buf0
    stage(0, 0);
    asm volatile("s_waitcnt vmcnt(0)" ::: "memory");
    __builtin_amdgcn_s_barrier();
    __builtin_amdgcn_sched_barrier(0);

    // Kchunk/32 is even for all KS (power of two <= 16)
    for (int kk = 0; kk < Kchunk; kk += 64) {
        KSTEP(0, 1, kk);
        KSTEP(1, 0, kk + 32);
    }
#undef KSTEP

    // write G partial; C-layout: col = lane&15, row = (lane>>4)*4 + reg
    size_t gb = ((size_t)(ks * B_ + b) * C_ + it * 128) * C_ + jt * 128;
#pragma unroll
    for (int mf = 0; mf < 2; ++mf)
#pragma unroll
        for (int nf = 0; nf < 4; ++nf) {
            int rr = wm * 32 + mf * 16 + (lane >> 4) * 4;
            int cc = wn * 64 + nf * 16 + (lane & 15);
#pragma unroll
            for (int r = 0; r < 4; ++r)
                Gp[gb + (size_t)(rr + r) * C_ + cc] = acc[mf][nf][r];
        }

    // norm partials from fragment coverage:
    // waves with wn==0 saw every A element of rows [wm*32, wm*32+32) exactly once;
    // waves with wm==0 saw every B element of rows [wn*64, wn*64+64) exactly once.
#pragma unroll
    for (int mf = 0; mf < 2; ++mf) {
        float s = sA[mf];
        s += __shfl_xor(s, 16);
        s += __shfl_xor(s, 32);
        if (jt == 0 && wn == 0 && lane < 16)
            x2p[(ks * B_ + b) * C_ + it * 128 + wm * 32 + mf * 16 + lane] = s;
    }
#pragma unroll
    for (int nf = 0; nf < 4; ++nf) {
        float s = sB[nf];
        s += __shfl_xor(s, 16);
        s += __shfl_xor(s, 32);
        if (it == 0 && wm == 0 && lane < 16)
            y2p[(ks * B_ + b) * C_ + jt * 128 + wn * 64 + nf * 16 + lane] = s;
    }
}

// ---------------- kernel 2: reduce split-K, d2 = x2+y2-2G, argmin over j (tie -> smaller j) ----------------
__global__ __launch_bounds__(256) void argmin_kernel(const float* __restrict__ Gp,
                                                     const float* __restrict__ x2p,
                                                     const float* __restrict__ y2p,
                                                     float* __restrict__ minval,
                                                     int* __restrict__ minidx,
                                                     int KS) {
    int bi = blockIdx.x;           // b*C + i
    int b = bi >> 8;
    int i = bi & 255;
    int j = threadIdx.x;           // 0..255 == C

    float g = 0.f, sx = 0.f, sy = 0.f;
    for (int ks = 0; ks < KS; ++ks) {
        g  += Gp[((size_t)(ks * B_ + b) * C_ + i) * C_ + j];
        sx += x2p[(ks * B_ + b) * C_ + i];
        sy += y2p[(ks * B_ + b) * C_ + j];
    }

    float v = sx + sy - 2.f * g;
    int idx = j;
#pragma unroll
    for (int off = 32; off > 0; off >>= 1) {
        float v2 = __shfl_down(v, off);
        int i2 = __shfl_down(idx, off);
        if (v2 < v || (v2 == v && i2 < idx)) { v = v2; idx = i2; }
    }
    __shared__ float wv[4];
    __shared__ int wi[4];
    int lane = threadIdx.x & 63, wid = threadIdx.x >> 6;
    if (lane == 0) { wv[wid] = v; wi[wid] = idx; }
    __syncthreads();
    if (threadIdx.x == 0) {
        for (int w = 1; w < 4; ++w)
            if (wv[w] < v || (wv[w] == v && wi[w] < idx)) { v = wv[w]; idx = wi[w]; }
        minval[bi] = v;
        minidx[bi] = idx;
    }
}

// ---------------- kernel 3: per-batch stable top-128 selection + compaction ----------------
__global__ __launch_bounds__(256) void select_kernel(const float* __restrict__ minval,
                                                     const int* __restrict__ minidx,
                                                     int* __restrict__ nn) {
    int b = blockIdx.x;
    int i = threadIdx.x;           // channel
    __shared__ float vals[C_];
    __shared__ int wcnt[4];

    float v = minval[b * C_ + i];
    vals[i] = v;
    __syncthreads();

    int rank = 0;
    for (int tt = 0; tt < C_; ++tt) {
        float u = vals[tt];
        rank += (u < v) || (u == v && tt < i);
    }
    bool flag = rank < NM_;

    unsigned long long m = __ballot(flag);
    int lane = i & 63, wid = i >> 6;
    if (lane == 0) wcnt[wid] = (int)__popcll(m);
    __syncthreads();
    int off = 0;
    for (int w = 0; w < wid; ++w) off += wcnt[w];
    int pos = off + (int)__popcll(m & ((1ULL << lane) - 1ULL));
    if (flag) nn[b * NM_ + pos] = minidx[b * C_ + i];
}

// ---------------- kernel 4: gather selected Ym rows ----------------
__global__ __launch_bounds__(256) void gather_kernel(const float* __restrict__ Y,
                                                     const int* __restrict__ nn,
                                                     float* __restrict__ out) {
    int blk = blockIdx.x;
    int b = blk >> 7;
    int m = blk & 127;
    int src = nn[b * NM_ + m];
    const float4* s = (const float4*)(Y + ((size_t)b * C_ + src) * N_);
    float4* d = (float4*)(out + ((size_t)b * NM_ + m) * N_);
    for (int tt = threadIdx.x; tt < N_ / 4; tt += 256) d[tt] = s[tt];
}

extern "C" void kernel_launch(void* const* d_in, const int* in_sizes, int n_in,
                              void* d_out, int out_size, void* d_ws, size_t ws_size,
                              hipStream_t stream) {
    const float* X = (const float*)d_in[0];
    const float* Y = (const float*)d_in[1];
    float* out = (float*)d_out;

    // choose split-K factor by available workspace (exact need per KS)
    size_t favail = ws_size / 4;
    int KS = 1;
    while (KS < 16) {
        int KS2 = KS * 2;
        size_t need = (size_t)KS2 * B_ * C_ * C_          // Gp
                    + (size_t)KS2 * 2 * B_ * C_           // x2p, y2p
                    + 2 * B_ * C_ + B_ * NM_;             // minval/minidx/nn
        if (need > favail) break;
        KS = KS2;
    }
    int Kchunk = N_ / KS;

    float* minval = (float*)d_ws;
    int* minidx = (int*)(minval + B_ * C_);
    int* nn = minidx + B_ * C_;
    float* x2p = (float*)(nn + B_ * NM_);
    float* y2p = x2p + (size_t)KS * B_ * C_;
    float* Gp = y2p + (size_t)KS * B_ * C_;

    hipLaunchKernelGGL(gemm_f16_kernel, dim3(KS * 32), dim3(512), 0, stream, X, Y, Gp, x2p, y2p, Kchunk);
    hipLaunchKernelGGL(argmin_kernel, dim3(B_ * C_), dim3(256), 0, stream, Gp, x2p, y2p, minval, minidx, KS);
    hipLaunchKernelGGL(select_kernel, dim3(B_), dim3(256), 0, stream, minval, minidx, nn);
    hipLaunchKernelGGL(gather_kernel, dim3(B_ * NM_), dim3(256), 0, stream, Y, nn, out);
}

// Round 8
// 160.492 us; speedup vs baseline: 1.6324x; 1.6324x over previous
//
#include <hip/hip_runtime.h>

#define B_  8
#define C_  256
#define N_  16384
#define NM_ 128

typedef _Float16 f16x8 __attribute__((ext_vector_type(8)));
typedef float    f32x4 __attribute__((ext_vector_type(4)));

#define MFMA16(A, Bf, Cc) __builtin_amdgcn_mfma_f32_16x16x32_f16((A), (Bf), (Cc), 0, 0, 0)

// ---------------- kernel 1: split-K fp16x2 MFMA GEMM, 8-phase-template structure ----------------
// BM=256 (all i) x BN=128 (jt half) x BK=32. 512 threads = 8 waves (4 wm x 2 wn),
// per-wave 64x64 output (acc 64 VGPR). 1 block/CU, 96 KB LDS, waves_per_eu(2,2) -> 256 VGPR budget.
// Per K-step: two template phases {ds_read subtile; stage-issue; barrier; lgkm0; SB; prio1; 24 MFMA; prio0; barrier}.
__global__ __launch_bounds__(512)
__attribute__((amdgpu_waves_per_eu(2, 2)))
void gemm_f16_kernel(const float* __restrict__ X,
                     const float* __restrict__ Y,
                     float* __restrict__ Gp,
                     float* __restrict__ x2p,
                     float* __restrict__ y2p,
                     int Kchunk) {
    __shared__ _Float16 aH[2][256][32];   // 32 KB
    __shared__ _Float16 aL[2][256][32];   // 32 KB
    __shared__ _Float16 bH[2][128][32];   // 16 KB
    __shared__ _Float16 bL[2][128][32];   // 16 KB

    int lin = blockIdx.x;
    int jt = lin & 1, b = (lin >> 1) & 7, ks = lin >> 4;
    int k0 = ks * Kchunk;

    int t = threadIdx.x;
    int lane = t & 63;
    int wid = t >> 6;                 // 8 waves
    int wm = wid >> 1, wn = wid & 1;  // wave tile: rows wm*64.., cols wn*64..
    int fr = lane & 15, fk = (lane >> 4) * 8;

    const float* Xb = X + (size_t)(b * C_) * N_;
    const float* Yb = Y + (size_t)(b * C_ + jt * 128) * N_;

    // staging shares: A: 16 floats (row t>>1, k-half t&1); B: 8 floats (row t>>2, k-quarter t&3)
    int arow = t >> 1, akh = t & 1;
    int brow = t >> 2, bkq = t & 3;
    const float* ax = Xb + (size_t)arow * N_ + k0 + akh * 16;
    const float* by = Yb + (size_t)brow * N_ + k0 + bkq * 8;

    f32x4 acc[4][2] = {};
    float sx = 0.f, sy = 0.f;
    float4 VA[4], VB[2];

    auto issue = [&](int koff) {
        VA[0] = *(const float4*)(ax + koff);
        VA[1] = *(const float4*)(ax + koff + 4);
        VA[2] = *(const float4*)(ax + koff + 8);
        VA[3] = *(const float4*)(ax + koff + 12);
        VB[0] = *(const float4*)(by + koff);
        VB[1] = *(const float4*)(by + koff + 4);
    };

    auto convert_store = [&](int wr) {
        float fa[16];
        *(float4*)&fa[0]  = VA[0]; *(float4*)&fa[4]  = VA[1];
        *(float4*)&fa[8]  = VA[2]; *(float4*)&fa[12] = VA[3];
        f16x8 h0, h1, l0, l1;
#pragma unroll
        for (int e = 0; e < 8; ++e) {
            float v = fa[e];
            _Float16 h = (_Float16)v;
            h0[e] = h; l0[e] = (_Float16)(v - (float)h); sx += v * v;
            float v2 = fa[e + 8];
            _Float16 h2 = (_Float16)v2;
            h1[e] = h2; l1[e] = (_Float16)(v2 - (float)h2); sx += v2 * v2;
        }
        *(f16x8*)&aH[wr][arow][akh * 16]     = h0;
        *(f16x8*)&aH[wr][arow][akh * 16 + 8] = h1;
        *(f16x8*)&aL[wr][arow][akh * 16]     = l0;
        *(f16x8*)&aL[wr][arow][akh * 16 + 8] = l1;
        float fb[8];
        *(float4*)&fb[0] = VB[0]; *(float4*)&fb[4] = VB[1];
        f16x8 bh, bl;
#pragma unroll
        for (int e = 0; e < 8; ++e) {
            float w = fb[e];
            _Float16 h = (_Float16)w;
            bh[e] = h; bl[e] = (_Float16)(w - (float)h); sy += w * w;
        }
        *(f16x8*)&bH[wr][brow][bkq * 8] = bh;
        *(f16x8*)&bL[wr][brow][bkq * 8] = bl;
    };

#define KSTEP(RD, WR, KOFF)                                                                        \
    {                                                                                              \
        /* ---------- phase A: A-frags + B0/B1 reads, issue next loads, MFMA nf=0,1 ---------- */  \
        f16x8 aHi[4], aLo[4];                                                                      \
        _Pragma("unroll")                                                                          \
        for (int mf = 0; mf < 4; ++mf) {                                                           \
            aHi[mf] = *(const f16x8*)&aH[RD][wm * 64 + mf * 16 + fr][fk];                          \
            aLo[mf] = *(const f16x8*)&aL[RD][wm * 64 + mf * 16 + fr][fk];                          \
        }                                                                                          \
        f16x8 b0H = *(const f16x8*)&bH[RD][wn * 64 +  0 + fr][fk];                                 \
        f16x8 b0L = *(const f16x8*)&bL[RD][wn * 64 +  0 + fr][fk];                                 \
        f16x8 b1H = *(const f16x8*)&bH[RD][wn * 64 + 16 + fr][fk];                                 \
        f16x8 b1L = *(const f16x8*)&bL[RD][wn * 64 + 16 + fr][fk];                                 \
        if ((KOFF) + 32 < Kchunk) issue((KOFF) + 32);                                              \
        __builtin_amdgcn_sched_barrier(0);                                                         \
        __builtin_amdgcn_s_barrier();                                                              \
        asm volatile("s_waitcnt lgkmcnt(0)" ::: "memory");                                         \
        __builtin_amdgcn_sched_barrier(0);                                                         \
        __builtin_amdgcn_s_setprio(1);                                                             \
        _Pragma("unroll") for (int mf = 0; mf < 4; ++mf) acc[mf][0] = MFMA16(aHi[mf], b0H, acc[mf][0]); \
        _Pragma("unroll") for (int mf = 0; mf < 4; ++mf) acc[mf][1] = MFMA16(aHi[mf], b1H, acc[mf][1]); \
        _Pragma("unroll") for (int mf = 0; mf < 4; ++mf) acc[mf][0] = MFMA16(aHi[mf], b0L, acc[mf][0]); \
        _Pragma("unroll") for (int mf = 0; mf < 4; ++mf) acc[mf][1] = MFMA16(aHi[mf], b1L, acc[mf][1]); \
        _Pragma("unroll") for (int mf = 0; mf < 4; ++mf) acc[mf][0] = MFMA16(aLo[mf], b0H, acc[mf][0]); \
        _Pragma("unroll") for (int mf = 0; mf < 4; ++mf) acc[mf][1] = MFMA16(aLo[mf], b1H, acc[mf][1]); \
        __builtin_amdgcn_s_setprio(0);                                                             \
        __builtin_amdgcn_s_barrier();                                                              \
        /* ---------- phase B: B2/B3 reads, convert+write next tile, MFMA nf=2,3 ---------- */     \
        f16x8 b2H = *(const f16x8*)&bH[RD][wn * 64 + 32 + fr][fk];                                 \
        f16x8 b2L = *(const f16x8*)&bL[RD][wn * 64 + 32 + fr][fk];                                 \
        f16x8 b3H = *(const f16x8*)&bH[RD][wn * 64 + 48 + fr][fk];                                 \
        f16x8 b3L = *(const f16x8*)&bL[RD][wn * 64 + 48 + fr][fk];                                 \
        if ((KOFF) + 32 < Kchunk) {                                                                \
            asm volatile("s_waitcnt vmcnt(0)" ::: "memory");                                       \
            convert_store(WR);                                                                     \
        }                                                                                          \
        asm volatile("s_waitcnt lgkmcnt(0)" ::: "memory");                                         \
        __builtin_amdgcn_s_barrier();                                                              \
        __builtin_amdgcn_sched_barrier(0);                                                         \
        __builtin_amdgcn_s_setprio(1);                                                             \
        _Pragma("unroll") for (int mf = 0; mf < 4; ++mf) acc[mf][0] = MFMA16(aHi[mf], b2H, acc[mf][0]); \
        _Pragma("unroll") for (int mf = 0; mf < 4; ++mf) acc[mf][1] = MFMA16(aHi[mf], b3H, acc[mf][1]); \
        _Pragma("unroll") for (int mf = 0; mf < 4; ++mf) acc[mf][0] = MFMA16(aHi[mf], b2L, acc[mf][0]); \
        _Pragma("unroll") for (int mf = 0; mf < 4; ++mf) acc[mf][1] = MFMA16(aHi[mf], b3L, acc[mf][1]); \
        _Pragma("unroll") for (int mf = 0; mf < 4; ++mf) acc[mf][0] = MFMA16(aLo[mf], b2H, acc[mf][0]); \
        _Pragma("unroll") for (int mf = 0; mf < 4; ++mf) acc[mf][1] = MFMA16(aLo[mf], b3H, acc[mf][1]); \
        __builtin_amdgcn_s_setprio(0);                                                             \
        __builtin_amdgcn_s_barrier();                                                              \
    }
    // NOTE on nf mapping: phase A handles B sub-columns 0,16 (acc[.][0] with b0*, acc[.][1] with b1*),
    // phase B handles 32,48. acc[mf][0] accumulates cols wn*64+{0,32}+... -- WRONG if mixed.
    // To keep it right we use 4 separate acc columns:

    // prologue: stage chunk 0 into buf0
    issue(0);
    asm volatile("s_waitcnt vmcnt(0)" ::: "memory");
    convert_store(0);
    asm volatile("s_waitcnt lgkmcnt(0)" ::: "memory");
    __builtin_amdgcn_s_barrier();
    __builtin_amdgcn_sched_barrier(0);

    // steps: Kchunk/32 is even (Kchunk >= 1024, power-of-two split)
    for (int kk = 0; kk < Kchunk; kk += 64) {
        KSTEP(0, 1, kk);
        KSTEP(1, 0, kk + 32);
    }
#undef KSTEP

    // write G partial; C-layout: col = lane&15, row = (lane>>4)*4 + r
    // acc[mf][0] holds cols {0,32}+... NO -- phase A used acc[mf][0] for nf=0 and phase B reused
    // acc[mf][0] for nf=2: they accumulate into the SAME register but different output columns!
    // Correction applied below by having used distinct col groups: phase A nf pair (0,1) ->
    // acc[.][0]/acc[.][1]; phase B nf pair (2,3) -> ALSO acc[.][0]/acc[.][1]. This would be a bug,
    // so the epilogue treats acc as summed pairs -- invalid. Instead we avoided the bug by noting
    // b0/b2 feed DIFFERENT dot-products; we must keep 4 acc columns. See acc4 below.
    // (acc was declared [4][2]; the KSTEP above was generated with pair-reuse -- fix: we allocated
    //  [4][2] but phase B must use columns 2,3. The macro text above uses acc[mf][0/1] in both
    //  phases, which double-books. The real fix: declare acc[4][4] and phase B writes [2]/[3].)
    {}

    // norm partial reduction + stores
    sx += __shfl_xor(sx, 1);
    if (jt == 0 && !(t & 1)) x2p[(ks * B_ + b) * C_ + arow] = sx;
    sy += __shfl_xor(sy, 1);
    sy += __shfl_xor(sy, 2);
    if (!(t & 3)) y2p[(ks * B_ + b) * C_ + jt * 128 + brow] = sy;

    size_t gbase = (size_t)(ks * B_ + b) * C_ * C_ + (size_t)jt * 128;
#pragma unroll
    for (int mf = 0; mf < 4; ++mf)
#pragma unroll
        for (int nf = 0; nf < 2; ++nf) {
            int rr = wm * 64 + mf * 16 + (lane >> 4) * 4;
            int cc = wn * 64 + nf * 16 + (lane & 15);
#pragma unroll
            for (int r = 0; r < 4; ++r)
                Gp[gbase + (size_t)(rr + r) * C_ + cc] = acc[mf][nf][r];
        }
}

// The acc double-booking noted above is fatal; this file replaces gemm_f16_kernel with a fixed
// version below and launches THAT one. (Kept the text above minimal-diff; the fixed kernel is
// the one actually used.)

__global__ __launch_bounds__(512)
__attribute__((amdgpu_waves_per_eu(2, 2)))
void gemm_f16_kernel_v2(const float* __restrict__ X,
                        const float* __restrict__ Y,
                        float* __restrict__ Gp,
                        float* __restrict__ x2p,
                        float* __restrict__ y2p,
                        int Kchunk) {
    __shared__ _Float16 aH[2][256][32];
    __shared__ _Float16 aL[2][256][32];
    __shared__ _Float16 bH[2][128][32];
    __shared__ _Float16 bL[2][128][32];

    int lin = blockIdx.x;
    int jt = lin & 1, b = (lin >> 1) & 7, ks = lin >> 4;
    int k0 = ks * Kchunk;

    int t = threadIdx.x;
    int lane = t & 63;
    int wid = t >> 6;
    int wm = wid >> 1, wn = wid & 1;
    int fr = lane & 15, fk = (lane >> 4) * 8;

    const float* Xb = X + (size_t)(b * C_) * N_;
    const float* Yb = Y + (size_t)(b * C_ + jt * 128) * N_;

    int arow = t >> 1, akh = t & 1;
    int brow = t >> 2, bkq = t & 3;
    const float* ax = Xb + (size_t)arow * N_ + k0 + akh * 16;
    const float* by = Yb + (size_t)brow * N_ + k0 + bkq * 8;

    f32x4 acc[4][4] = {};
    float sx = 0.f, sy = 0.f;
    float4 VA[4], VB[2];

    auto issue = [&](int koff) {
        VA[0] = *(const float4*)(ax + koff);
        VA[1] = *(const float4*)(ax + koff + 4);
        VA[2] = *(const float4*)(ax + koff + 8);
        VA[3] = *(const float4*)(ax + koff + 12);
        VB[0] = *(const float4*)(by + koff);
        VB[1] = *(const float4*)(by + koff + 4);
    };

    auto convert_store = [&](int wr) {
        float fa[16];
        *(float4*)&fa[0]  = VA[0]; *(float4*)&fa[4]  = VA[1];
        *(float4*)&fa[8]  = VA[2]; *(float4*)&fa[12] = VA[3];
        f16x8 h0, h1, l0, l1;
#pragma unroll
        for (int e = 0; e < 8; ++e) {
            float v = fa[e];
            _Float16 h = (_Float16)v;
            h0[e] = h; l0[e] = (_Float16)(v - (float)h); sx += v * v;
            float v2 = fa[e + 8];
            _Float16 h2 = (_Float16)v2;
            h1[e] = h2; l1[e] = (_Float16)(v2 - (float)h2); sx += v2 * v2;
        }
        *(f16x8*)&aH[wr][arow][akh * 16]     = h0;
        *(f16x8*)&aH[wr][arow][akh * 16 + 8] = h1;
        *(f16x8*)&aL[wr][arow][akh * 16]     = l0;
        *(f16x8*)&aL[wr][arow][akh * 16 + 8] = l1;
        float fb[8];
        *(float4*)&fb[0] = VB[0]; *(float4*)&fb[4] = VB[1];
        f16x8 bh, bl;
#pragma unroll
        for (int e = 0; e < 8; ++e) {
            float w = fb[e];
            _Float16 h = (_Float16)w;
            bh[e] = h; bl[e] = (_Float16)(w - (float)h); sy += w * w;
        }
        *(f16x8*)&bH[wr][brow][bkq * 8] = bh;
        *(f16x8*)&bL[wr][brow][bkq * 8] = bl;
    };

#define KSTEP(RD, WR, KOFF)                                                                        \
    {                                                                                              \
        f16x8 aHi[4], aLo[4];                                                                      \
        _Pragma("unroll")                                                                          \
        for (int mf = 0; mf < 4; ++mf) {                                                           \
            aHi[mf] = *(const f16x8*)&aH[RD][wm * 64 + mf * 16 + fr][fk];                          \
            aLo[mf] = *(const f16x8*)&aL[RD][wm * 64 + mf * 16 + fr][fk];                          \
        }                                                                                          \
        f16x8 b0H = *(const f16x8*)&bH[RD][wn * 64 +  0 + fr][fk];                                 \
        f16x8 b0L = *(const f16x8*)&bL[RD][wn * 64 +  0 + fr][fk];                                 \
        f16x8 b1H = *(const f16x8*)&bH[RD][wn * 64 + 16 + fr][fk];                                 \
        f16x8 b1L = *(const f16x8*)&bL[RD][wn * 64 + 16 + fr][fk];                                 \
        if ((KOFF) + 32 < Kchunk) issue((KOFF) + 32);                                              \
        __builtin_amdgcn_sched_barrier(0);                                                         \
        __builtin_amdgcn_s_barrier();                                                              \
        asm volatile("s_waitcnt lgkmcnt(0)" ::: "memory");                                         \
        __builtin_amdgcn_sched_barrier(0);                                                         \
        __builtin_amdgcn_s_setprio(1);                                                             \
        _Pragma("unroll") for (int mf = 0; mf < 4; ++mf) acc[mf][0] = MFMA16(aHi[mf], b0H, acc[mf][0]); \
        _Pragma("unroll") for (int mf = 0; mf < 4; ++mf) acc[mf][1] = MFMA16(aHi[mf], b1H, acc[mf][1]); \
        _Pragma("unroll") for (int mf = 0; mf < 4; ++mf) acc[mf][0] = MFMA16(aHi[mf], b0L, acc[mf][0]); \
        _Pragma("unroll") for (int mf = 0; mf < 4; ++mf) acc[mf][1] = MFMA16(aHi[mf], b1L, acc[mf][1]); \
        _Pragma("unroll") for (int mf = 0; mf < 4; ++mf) acc[mf][0] = MFMA16(aLo[mf], b0H, acc[mf][0]); \
        _Pragma("unroll") for (int mf = 0; mf < 4; ++mf) acc[mf][1] = MFMA16(aLo[mf], b1H, acc[mf][1]); \
        __builtin_amdgcn_s_setprio(0);                                                             \
        __builtin_amdgcn_s_barrier();                                                              \
        f16x8 b2H = *(const f16x8*)&bH[RD][wn * 64 + 32 + fr][fk];                                 \
        f16x8 b2L = *(const f16x8*)&bL[RD][wn * 64 + 32 + fr][fk];                                 \
        f16x8 b3H = *(const f16x8*)&bH[RD][wn * 64 + 48 + fr][fk];                                 \
        f16x8 b3L = *(const f16x8*)&bL[RD][wn * 64 + 48 + fr][fk];                                 \
        if ((KOFF) + 32 < Kchunk) {                                                                \
            asm volatile("s_waitcnt vmcnt(0)" ::: "memory");                                       \
            convert_store(WR);                                                                     \
        }                                                                                          \
        asm volatile("s_waitcnt lgkmcnt(0)" ::: "memory");                                         \
        __builtin_amdgcn_s_barrier();                                                              \
        __builtin_amdgcn_sched_barrier(0);                                                         \
        __builtin_amdgcn_s_setprio(1);                                                             \
        _Pragma("unroll") for (int mf = 0; mf < 4; ++mf) acc[mf][2] = MFMA16(aHi[mf], b2H, acc[mf][2]); \
        _Pragma("unroll") for (int mf = 0; mf < 4; ++mf) acc[mf][3] = MFMA16(aHi[mf], b3H, acc[mf][3]); \
        _Pragma("unroll") for (int mf = 0; mf < 4; ++mf) acc[mf][2] = MFMA16(aHi[mf], b2L, acc[mf][2]); \
        _Pragma("unroll") for (int mf = 0; mf < 4; ++mf) acc[mf][3] = MFMA16(aHi[mf], b3L, acc[mf][3]); \
        _Pragma("unroll") for (int mf = 0; mf < 4; ++mf) acc[mf][2] = MFMA16(aLo[mf], b2H, acc[mf][2]); \
        _Pragma("unroll") for (int mf = 0; mf < 4; ++mf) acc[mf][3] = MFMA16(aLo[mf], b3H, acc[mf][3]); \
        __builtin_amdgcn_s_setprio(0);                                                             \
        __builtin_amdgcn_s_barrier();                                                              \
    }

    issue(0);
    asm volatile("s_waitcnt vmcnt(0)" ::: "memory");
    convert_store(0);
    asm volatile("s_waitcnt lgkmcnt(0)" ::: "memory");
    __builtin_amdgcn_s_barrier();
    __builtin_amdgcn_sched_barrier(0);

    for (int kk = 0; kk < Kchunk; kk += 64) {
        KSTEP(0, 1, kk);
        KSTEP(1, 0, kk + 32);
    }
#undef KSTEP

    sx += __shfl_xor(sx, 1);
    if (jt == 0 && !(t & 1)) x2p[(ks * B_ + b) * C_ + arow] = sx;
    sy += __shfl_xor(sy, 1);
    sy += __shfl_xor(sy, 2);
    if (!(t & 3)) y2p[(ks * B_ + b) * C_ + jt * 128 + brow] = sy;

    size_t gbase = (size_t)(ks * B_ + b) * C_ * C_ + (size_t)jt * 128;
#pragma unroll
    for (int mf = 0; mf < 4; ++mf)
#pragma unroll
        for (int nf = 0; nf < 4; ++nf) {
            int rr = wm * 64 + mf * 16 + (lane >> 4) * 4;
            int cc = wn * 64 + nf * 16 + (lane & 15);
#pragma unroll
            for (int r = 0; r < 4; ++r)
                Gp[gbase + (size_t)(rr + r) * C_ + cc] = acc[mf][nf][r];
        }
}

// ---------------- kernel 2: reduce split-K, d2 = x2+y2-2G, argmin over j (tie -> smaller j) ----------------
__global__ __launch_bounds__(256) void argmin_kernel(const float* __restrict__ Gp,
                                                     const float* __restrict__ x2p,
                                                     const float* __restrict__ y2p,
                                                     float* __restrict__ minval,
                                                     int* __restrict__ minidx,
                                                     int KS) {
    int bi = blockIdx.x;           // b*C + i
    int b = bi >> 8;
    int i = bi & 255;
    int j = threadIdx.x;           // 0..255 == C

    float g = 0.f, sx = 0.f, sy = 0.f;
    for (int ks = 0; ks < KS; ++ks) {
        g  += Gp[((size_t)(ks * B_ + b) * C_ + i) * C_ + j];
        sx += x2p[(ks * B_ + b) * C_ + i];
        sy += y2p[(ks * B_ + b) * C_ + j];
    }

    float v = sx + sy - 2.f * g;
    int idx = j;
#pragma unroll
    for (int off = 32; off > 0; off >>= 1) {
        float v2 = __shfl_down(v, off);
        int i2 = __shfl_down(idx, off);
        if (v2 < v || (v2 == v && i2 < idx)) { v = v2; idx = i2; }
    }
    __shared__ float wv[4];
    __shared__ int wi[4];
    int lane = threadIdx.x & 63, wid = threadIdx.x >> 6;
    if (lane == 0) { wv[wid] = v; wi[wid] = idx; }
    __syncthreads();
    if (threadIdx.x == 0) {
        for (int w = 1; w < 4; ++w)
            if (wv[w] < v || (wv[w] == v && wi[w] < idx)) { v = wv[w]; idx = wi[w]; }
        minval[bi] = v;
        minidx[bi] = idx;
    }
}

// ---------------- kernel 3: per-batch stable top-128 selection + compaction ----------------
__global__ __launch_bounds__(256) void select_kernel(const float* __restrict__ minval,
                                                     const int* __restrict__ minidx,
                                                     int* __restrict__ nn) {
    int b = blockIdx.x;
    int i = threadIdx.x;           // channel
    __shared__ float vals[C_];
    __shared__ int wcnt[4];

    float v = minval[b * C_ + i];
    vals[i] = v;
    __syncthreads();

    int rank = 0;
    for (int tt = 0; tt < C_; ++tt) {
        float u = vals[tt];
        rank += (u < v) || (u == v && tt < i);
    }
    bool flag = rank < NM_;

    unsigned long long m = __ballot(flag);
    int lane = i & 63, wid = i >> 6;
    if (lane == 0) wcnt[wid] = (int)__popcll(m);
    __syncthreads();
    int off = 0;
    for (int w = 0; w < wid; ++w) off += wcnt[w];
    int pos = off + (int)__popcll(m & ((1ULL << lane) - 1ULL));
    if (flag) nn[b * NM_ + pos] = minidx[b * C_ + i];
}

// ---------------- kernel 4: gather selected Ym rows ----------------
__global__ __launch_bounds__(256) void gather_kernel(const float* __restrict__ Y,
                                                     const int* __restrict__ nn,
                                                     float* __restrict__ out) {
    int blk = blockIdx.x;
    int b = blk >> 7;
    int m = blk & 127;
    int src = nn[b * NM_ + m];
    const float4* s = (const float4*)(Y + ((size_t)b * C_ + src) * N_);
    float4* d = (float4*)(out + ((size_t)b * NM_ + m) * N_);
    for (int tt = threadIdx.x; tt < N_ / 4; tt += 256) d[tt] = s[tt];
}

extern "C" void kernel_launch(void* const* d_in, const int* in_sizes, int n_in,
                              void* d_out, int out_size, void* d_ws, size_t ws_size,
                              hipStream_t stream) {
    const float* X = (const float*)d_in[0];
    const float* Y = (const float*)d_in[1];
    float* out = (float*)d_out;

    // choose split-K factor by available workspace (exact need per KS)
    size_t favail = ws_size / 4;
    int KS = 1;
    while (KS < 16) {
        int KS2 = KS * 2;
        size_t need = (size_t)KS2 * B_ * C_ * C_          // Gp
                    + (size_t)KS2 * 2 * B_ * C_           // x2p, y2p
                    + 2 * B_ * C_ + B_ * NM_;             // minval/minidx/nn
        if (need > favail) break;
        KS = KS2;
    }
    int Kchunk = N_ / KS;

    float* minval = (float*)d_ws;
    int* minidx = (int*)(minval + B_ * C_);
    int* nn = minidx + B_ * C_;
    float* x2p = (float*)(nn + B_ * NM_);
    float* y2p = x2p + (size_t)KS * B_ * C_;
    float* Gp = y2p + (size_t)KS * B_ * C_;

    hipLaunchKernelGGL(gemm_f16_kernel_v2, dim3(KS * 16), dim3(512), 0, stream, X, Y, Gp, x2p, y2p, Kchunk);
    hipLaunchKernelGGL(argmin_kernel, dim3(B_ * C_), dim3(256), 0, stream, Gp, x2p, y2p, minval, minidx, KS);
    hipLaunchKernelGGL(select_kernel, dim3(B_), dim3(256), 0, stream, minval, minidx, nn);
    hipLaunchKernelGGL(gather_kernel, dim3(B_ * NM_), dim3(256), 0, stream, Y, nn, out);
}

// Round 9
// 146.534 us; speedup vs baseline: 1.7879x; 1.0953x over previous
//
#include <hip/hip_runtime.h>

#define B_  8
#define C_  256
#define N_  16384
#define NM_ 128

typedef _Float16 f16x8 __attribute__((ext_vector_type(8)));
typedef float    f32x4 __attribute__((ext_vector_type(4)));

#define MFMA16(A, Bf, Cc) __builtin_amdgcn_mfma_f32_16x16x32_f16((A), (Bf), (Cc), 0, 0, 0)
#define AS1 __attribute__((address_space(1)))
#define AS3 __attribute__((address_space(3)))

// convert 8 staged fp32 (two f32x4) into hi/lo f16x8, accumulating squared-norm
#define CVT(P0, P1, HI, LO, SQ)                           \
    {                                                     \
        float tmp_[8];                                    \
        *(f32x4*)&tmp_[0] = (P0);                         \
        *(f32x4*)&tmp_[4] = (P1);                         \
        _Pragma("unroll")                                 \
        for (int e_ = 0; e_ < 8; ++e_) {                  \
            float v_ = tmp_[e_];                          \
            _Float16 h_ = (_Float16)v_;                   \
            (HI)[e_] = h_;                                \
            (LO)[e_] = (_Float16)(v_ - (float)h_);        \
            (SQ) += v_ * v_;                              \
        }                                                 \
    }

// ---------------- kernel 1: split-K fp16x2 MFMA GEMM, fp32 DMA ring depth 3 ----------------
// BM=256 x BN=128 x BK=32. 512 threads = 8 waves (4 wm x 2 wn), wave = 64x64 (acc 64 VGPR).
// global_load_lds stages raw fp32 into a 3-deep LDS ring; counted vmcnt(6) never waits on
// fresh loads. Conversion to f16 hi/lo happens at consume. Swizzle unit^=(row&3) both sides.
__global__ __launch_bounds__(512)
__attribute__((amdgpu_waves_per_eu(2, 2)))
void gemm_f16_kernel(const float* __restrict__ X,
                     const float* __restrict__ Y,
                     float* __restrict__ Gp,
                     float* __restrict__ x2p,
                     float* __restrict__ y2p,
                     int Kchunk) {
    __shared__ float A_lds[3][256 * 32];   // 96 KB
    __shared__ float B_lds[3][128 * 32];   // 48 KB

    // XCD-aware block swizzle (grid = KS*16, always % 8 == 0)
    int cpx = gridDim.x >> 3;
    int lin = (blockIdx.x & 7) * cpx + (blockIdx.x >> 3);

    int jt = lin & 1, b = (lin >> 1) & 7, ks = lin >> 4;
    int k0 = ks * Kchunk;
    int nsteps = Kchunk >> 5;   // BK=32

    int t = threadIdx.x;
    int lane = t & 63;
    int wid = t >> 6;                  // 0..7
    int wm = wid >> 1, wn = wid & 1;   // wave tile 64x64 at (wm*64, wn*64)
    int fr = lane & 15, ug = lane >> 4;

    const float* Xb = X + (size_t)(b * C_) * N_;
    const float* Yb = Y + (size_t)(b * C_ + jt * 128) * N_;

    // DMA lane geometry: one op = 64 lanes x 16B = 8 rows x 128B
    int lrow = lane >> 3;      // row within op
    int lchk = lane & 7;       // 16B chunk within row
    int lhalf = lchk & 1;
    int luni = lchk >> 1;      // logical 32B unit (0..3)

    f32x4 acc[4][4] = {};
    float sA[4] = {0.f, 0.f, 0.f, 0.f};
    float sB[4] = {0.f, 0.f, 0.f, 0.f};

    auto issue = [&](int chunk, int sl) {
        int kbase = k0 + chunk * 32;
#pragma unroll
        for (int q = 0; q < 4; ++q) {                      // A: 32 rows / wave
            int r = wid * 32 + q * 8 + lrow;
            int kA = ((luni ^ (r & 3)) << 3) + lhalf * 4;  // pre-swizzled source
            __builtin_amdgcn_global_load_lds(
                (const AS1 void*)(Xb + (size_t)r * N_ + kbase + kA),
                (AS3 void*)&A_lds[sl][(wid * 32 + q * 8) * 32], 16, 0, 0);
        }
#pragma unroll
        for (int q = 0; q < 2; ++q) {                      // B: 16 rows / wave
            int r = wid * 16 + q * 8 + lrow;
            int kB = ((luni ^ (r & 3)) << 3) + lhalf * 4;
            __builtin_amdgcn_global_load_lds(
                (const AS1 void*)(Yb + (size_t)r * N_ + kbase + kB),
                (AS3 void*)&B_lds[sl][(wid * 16 + q * 8) * 32], 16, 0, 0);
        }
    };

    // prologue: chunks 0 and 1 in flight; wait chunk 0 (vmcnt(6): chunk 1 keeps flying)
    issue(0, 0);
    issue(1, 1);
    asm volatile("s_waitcnt vmcnt(6)" ::: "memory");
    __builtin_amdgcn_s_barrier();
    __builtin_amdgcn_sched_barrier(0);

    for (int i = 0; i < nsteps; ++i) {
        int sl = i % 3;
        // issue chunk i+2 into the slot freed by step i-1's end barrier
        if (i + 2 < nsteps) issue(i + 2, (i + 2) % 3);
        __builtin_amdgcn_sched_barrier(0);

        // A fragments: fp32 -> hi/lo f16 (persistent across nf loop)
        f16x8 aHi[4], aLo[4];
#pragma unroll
        for (int mf = 0; mf < 4; ++mf) {
            int r = wm * 64 + mf * 16 + fr;
            const float* p = &A_lds[sl][r * 32 + ((ug ^ (r & 3)) << 3)];
            f32x4 p0 = *(const f32x4*)p;
            f32x4 p1 = *(const f32x4*)(p + 4);
            CVT(p0, p1, aHi[mf], aLo[mf], sA[mf]);
        }
#pragma unroll
        for (int nf = 0; nf < 4; ++nf) {
            int r = wn * 64 + nf * 16 + fr;
            const float* p = &B_lds[sl][r * 32 + ((ug ^ (r & 3)) << 3)];
            f32x4 q0 = *(const f32x4*)p;
            f32x4 q1 = *(const f32x4*)(p + 4);
            f16x8 bHi, bLo;
            CVT(q0, q1, bHi, bLo, sB[nf]);
            __builtin_amdgcn_s_setprio(1);
            acc[0][nf] = MFMA16(aHi[0], bHi, acc[0][nf]);
            acc[1][nf] = MFMA16(aHi[1], bHi, acc[1][nf]);
            acc[2][nf] = MFMA16(aHi[2], bHi, acc[2][nf]);
            acc[3][nf] = MFMA16(aHi[3], bHi, acc[3][nf]);
            acc[0][nf] = MFMA16(aHi[0], bLo, acc[0][nf]);
            acc[1][nf] = MFMA16(aHi[1], bLo, acc[1][nf]);
            acc[2][nf] = MFMA16(aHi[2], bLo, acc[2][nf]);
            acc[3][nf] = MFMA16(aHi[3], bLo, acc[3][nf]);
            acc[0][nf] = MFMA16(aLo[0], bHi, acc[0][nf]);
            acc[1][nf] = MFMA16(aLo[1], bHi, acc[1][nf]);
            acc[2][nf] = MFMA16(aLo[2], bHi, acc[2][nf]);
            acc[3][nf] = MFMA16(aLo[3], bHi, acc[3][nf]);
            __builtin_amdgcn_s_setprio(0);
        }

        __builtin_amdgcn_sched_barrier(0);
        if (i + 2 < nsteps) {
            asm volatile("s_waitcnt vmcnt(6)" ::: "memory");   // chunk i+1 landed (mine)
        } else {
            asm volatile("s_waitcnt vmcnt(0)" ::: "memory");   // drain tail
        }
        __builtin_amdgcn_s_barrier();                          // everyone's chunk i+1 landed
        __builtin_amdgcn_sched_barrier(0);
    }

    // norm partials: each wave converted A rows [wm*64,+64) and B rows [wn*64,+64) fully;
    // reduce the 4 lanes {fr, fr+16, fr+32, fr+48} covering one row's k-slices.
#pragma unroll
    for (int mf = 0; mf < 4; ++mf) {
        float s = sA[mf];
        s += __shfl_xor(s, 16);
        s += __shfl_xor(s, 32);
        if (jt == 0 && wn == 0 && lane < 16)
            x2p[(ks * B_ + b) * C_ + wm * 64 + mf * 16 + lane] = s;
    }
#pragma unroll
    for (int nf = 0; nf < 4; ++nf) {
        float s = sB[nf];
        s += __shfl_xor(s, 16);
        s += __shfl_xor(s, 32);
        if (wm == 0 && lane < 16)
            y2p[(ks * B_ + b) * C_ + jt * 128 + wn * 64 + nf * 16 + lane] = s;
    }

    // write G partial; C-layout: col = lane&15, row = (lane>>4)*4 + r
    size_t gbase = (size_t)(ks * B_ + b) * C_ * C_ + (size_t)jt * 128;
#pragma unroll
    for (int mf = 0; mf < 4; ++mf)
#pragma unroll
        for (int nf = 0; nf < 4; ++nf) {
            int rr = wm * 64 + mf * 16 + (lane >> 4) * 4;
            int cc = wn * 64 + nf * 16 + (lane & 15);
#pragma unroll
            for (int r = 0; r < 4; ++r)
                Gp[gbase + (size_t)(rr + r) * C_ + cc] = acc[mf][nf][r];
        }
}

// ---------------- kernel 2: reduce split-K, d2 = x2+y2-2G, argmin over j (tie -> smaller j) ----------------
__global__ __launch_bounds__(256) void argmin_kernel(const float* __restrict__ Gp,
                                                     const float* __restrict__ x2p,
                                                     const float* __restrict__ y2p,
                                                     float* __restrict__ minval,
                                                     int* __restrict__ minidx,
                                                     int KS) {
    int bi = blockIdx.x;           // b*C + i
    int b = bi >> 8;
    int i = bi & 255;
    int j = threadIdx.x;           // 0..255 == C

    float g = 0.f, sx = 0.f, sy = 0.f;
    for (int ks = 0; ks < KS; ++ks) {
        g  += Gp[((size_t)(ks * B_ + b) * C_ + i) * C_ + j];
        sx += x2p[(ks * B_ + b) * C_ + i];
        sy += y2p[(ks * B_ + b) * C_ + j];
    }

    float v = sx + sy - 2.f * g;
    int idx = j;
#pragma unroll
    for (int off = 32; off > 0; off >>= 1) {
        float v2 = __shfl_down(v, off);
        int i2 = __shfl_down(idx, off);
        if (v2 < v || (v2 == v && i2 < idx)) { v = v2; idx = i2; }
    }
    __shared__ float wv[4];
    __shared__ int wi[4];
    int lane = threadIdx.x & 63, wid = threadIdx.x >> 6;
    if (lane == 0) { wv[wid] = v; wi[wid] = idx; }
    __syncthreads();
    if (threadIdx.x == 0) {
        for (int w = 1; w < 4; ++w)
            if (wv[w] < v || (wv[w] == v && wi[w] < idx)) { v = wv[w]; idx = wi[w]; }
        minval[bi] = v;
        minidx[bi] = idx;
    }
}

// ---------------- kernel 3: per-batch stable top-128 selection + compaction ----------------
__global__ __launch_bounds__(256) void select_kernel(const float* __restrict__ minval,
                                                     const int* __restrict__ minidx,
                                                     int* __restrict__ nn) {
    int b = blockIdx.x;
    int i = threadIdx.x;           // channel
    __shared__ float vals[C_];
    __shared__ int wcnt[4];

    float v = minval[b * C_ + i];
    vals[i] = v;
    __syncthreads();

    int rank = 0;
    for (int tt = 0; tt < C_; ++tt) {
        float u = vals[tt];
        rank += (u < v) || (u == v && tt < i);
    }
    bool flag = rank < NM_;

    unsigned long long m = __ballot(flag);
    int lane = i & 63, wid = i >> 6;
    if (lane == 0) wcnt[wid] = (int)__popcll(m);
    __syncthreads();
    int off = 0;
    for (int w = 0; w < wid; ++w) off += wcnt[w];
    int pos = off + (int)__popcll(m & ((1ULL << lane) - 1ULL));
    if (flag) nn[b * NM_ + pos] = minidx[b * C_ + i];
}

// ---------------- kernel 4: gather selected Ym rows ----------------
__global__ __launch_bounds__(256) void gather_kernel(const float* __restrict__ Y,
                                                     const int* __restrict__ nn,
                                                     float* __restrict__ out) {
    int blk = blockIdx.x;
    int b = blk >> 7;
    int m = blk & 127;
    int src = nn[b * NM_ + m];
    const float4* s = (const float4*)(Y + ((size_t)b * C_ + src) * N_);
    float4* d = (float4*)(out + ((size_t)b * NM_ + m) * N_);
    for (int tt = threadIdx.x; tt < N_ / 4; tt += 256) d[tt] = s[tt];
}

extern "C" void kernel_launch(void* const* d_in, const int* in_sizes, int n_in,
                              void* d_out, int out_size, void* d_ws, size_t ws_size,
                              hipStream_t stream) {
    const float* X = (const float*)d_in[0];
    const float* Y = (const float*)d_in[1];
    float* out = (float*)d_out;

    // choose split-K factor by available workspace (exact need per KS)
    size_t favail = ws_size / 4;
    int KS = 1;
    while (KS < 16) {
        int KS2 = KS * 2;
        size_t need = (size_t)KS2 * B_ * C_ * C_          // Gp
                    + (size_t)KS2 * 2 * B_ * C_           // x2p, y2p
                    + 2 * B_ * C_ + B_ * NM_;             // minval/minidx/nn
        if (need > favail) break;
        KS = KS2;
    }
    int Kchunk = N_ / KS;

    float* minval = (float*)d_ws;
    int* minidx = (int*)(minval + B_ * C_);
    int* nn = minidx + B_ * C_;
    float* x2p = (float*)(nn + B_ * NM_);
    float* y2p = x2p + (size_t)KS * B_ * C_;
    float* Gp = y2p + (size_t)KS * B_ * C_;

    hipLaunchKernelGGL(gemm_f16_kernel, dim3(KS * 16), dim3(512), 0, stream, X, Y, Gp, x2p, y2p, Kchunk);
    hipLaunchKernelGGL(argmin_kernel, dim3(B_ * C_), dim3(256), 0, stream, Gp, x2p, y2p, minval, minidx, KS);
    hipLaunchKernelGGL(select_kernel, dim3(B_), dim3(256), 0, stream, minval, minidx, nn);
    hipLaunchKernelGGL(gather_kernel, dim3(B_ * NM_), dim3(256), 0, stream, Y, nn, out);
}

// Round 10
// 130.567 us; speedup vs baseline: 2.0065x; 1.1223x over previous
//
#include <hip/hip_runtime.h>

#define B_  8
#define C_  256
#define N_  16384
#define NM_ 128

typedef _Float16 f16x8 __attribute__((ext_vector_type(8)));
typedef float    f32x4 __attribute__((ext_vector_type(4)));

#define MFMA16(A, Bf, Cc) __builtin_amdgcn_mfma_f32_16x16x32_f16((A), (Bf), (Cc), 0, 0, 0)
#define AS1 __attribute__((address_space(1)))
#define AS3 __attribute__((address_space(3)))

// convert 8 staged fp32 (two f32x4) into hi/lo f16x8, accumulating squared-norm
#define CVT(P0, P1, HI, LO, SQ)                           \
    {                                                     \
        float tmp_[8];                                    \
        *(f32x4*)&tmp_[0] = (P0);                         \
        *(f32x4*)&tmp_[4] = (P1);                         \
        _Pragma("unroll")                                 \
        for (int e_ = 0; e_ < 8; ++e_) {                  \
            float v_ = tmp_[e_];                          \
            _Float16 h_ = (_Float16)v_;                   \
            (HI)[e_] = h_;                                \
            (LO)[e_] = (_Float16)(v_ - (float)h_);        \
            (SQ) += v_ * v_;                              \
        }                                                 \
    }

// ---------------- kernel 1: split-K fp16x2 MFMA GEMM, 2 blocks/CU + DMA ring ----------------
// BM=128 x BN=128 x BK=32, 256 threads = 4 waves (2x2), each wave 64x64 (acc 64 VGPR).
// fp32 staged via global_load_lds into ring-2 LDS (64 KB/block -> 2 independent blocks/CU,
// which cover each other's end-of-step drains). 8-class XOR swizzle (16B unit ^= row&7)
// pre-applied on the DMA *source* address and re-applied on both ds_read halves (rule #21).
__global__ __launch_bounds__(256)
__attribute__((amdgpu_waves_per_eu(2, 2)))
void gemm_f16_kernel(const float* __restrict__ X,
                     const float* __restrict__ Y,
                     float* __restrict__ Gp,
                     float* __restrict__ x2p,
                     float* __restrict__ y2p,
                     int Kchunk) {
    __shared__ float A_lds[2][128 * 32];   // 32 KB
    __shared__ float B_lds[2][128 * 32];   // 32 KB

    // XCD-aware bijective swizzle (grid = KS*32, multiple of 8)
    int cpx = gridDim.x >> 3;
    int lin = (blockIdx.x & 7) * cpx + (blockIdx.x >> 3);

    int jt = lin & 1, it = (lin >> 1) & 1, b = (lin >> 2) & 7, ks = lin >> 5;
    int k0 = ks * Kchunk;
    int nsteps = Kchunk >> 5;   // BK=32

    int t = threadIdx.x;
    int lane = t & 63;
    int wid = t >> 6;                  // 0..3
    int wm = wid >> 1, wn = wid & 1;   // wave tile 64x64 at (wm*64, wn*64)
    int fr = lane & 15, ug = lane >> 4;

    const float* Xb = X + (size_t)(b * C_ + it * 128) * N_;
    const float* Yb = Y + (size_t)(b * C_ + jt * 128) * N_;

    // DMA lane geometry: one op = 64 lanes x 16B = 8 rows x 128B (contiguous LDS dest)
    int lrow = lane >> 3;              // row within op (== r&7 since op base % 8 == 0)
    int lchk = lane & 7;               // 16B chunk within row
    int lsw = (lchk ^ lrow) << 2;      // pre-swizzled source float offset

    f32x4 acc[4][4] = {};
    float sA[4] = {0.f, 0.f, 0.f, 0.f};
    float sB[4] = {0.f, 0.f, 0.f, 0.f};

    auto issue = [&](int chunk, int sl) {
        int kbase = k0 + chunk * 32;
#pragma unroll
        for (int q = 0; q < 4; ++q) {                      // A: 32 rows / wave
            int r = wid * 32 + q * 8 + lrow;
            __builtin_amdgcn_global_load_lds(
                (const AS1 void*)(Xb + (size_t)r * N_ + kbase + lsw),
                (AS3 void*)&A_lds[sl][(wid * 32 + q * 8) * 32], 16, 0, 0);
        }
#pragma unroll
        for (int q = 0; q < 4; ++q) {                      // B: 32 rows / wave
            int r = wid * 32 + q * 8 + lrow;
            __builtin_amdgcn_global_load_lds(
                (const AS1 void*)(Yb + (size_t)r * N_ + kbase + lsw),
                (AS3 void*)&B_lds[sl][(wid * 32 + q * 8) * 32], 16, 0, 0);
        }
    };

    // prologue: chunk 0 -> slot 0; wait it out (8 ops/wave), barrier
    issue(0, 0);
    if (nsteps > 1) issue(1, 1);
    asm volatile("s_waitcnt vmcnt(8)" ::: "memory");
    __builtin_amdgcn_s_barrier();
    __builtin_amdgcn_sched_barrier(0);

    for (int i = 0; i < nsteps; ++i) {
        int sl = i & 1;

        // A fragments: fp32 -> hi/lo f16 (swizzled ds_read: 16B unit (2ug+h) ^ (r&7))
        f16x8 aHi[4], aLo[4];
#pragma unroll
        for (int mf = 0; mf < 4; ++mf) {
            int r = wm * 64 + mf * 16 + fr;
            int s7 = r & 7;
            f32x4 p0 = *(const f32x4*)&A_lds[sl][r * 32 + (((ug * 2)     ^ s7) << 2)];
            f32x4 p1 = *(const f32x4*)&A_lds[sl][r * 32 + (((ug * 2 + 1) ^ s7) << 2)];
            CVT(p0, p1, aHi[mf], aLo[mf], sA[mf]);
        }
#pragma unroll
        for (int nf = 0; nf < 4; ++nf) {
            int r = wn * 64 + nf * 16 + fr;
            int s7 = r & 7;
            f32x4 q0 = *(const f32x4*)&B_lds[sl][r * 32 + (((ug * 2)     ^ s7) << 2)];
            f32x4 q1 = *(const f32x4*)&B_lds[sl][r * 32 + (((ug * 2 + 1) ^ s7) << 2)];
            f16x8 bHi, bLo;
            CVT(q0, q1, bHi, bLo, sB[nf]);
            __builtin_amdgcn_s_setprio(1);
            acc[0][nf] = MFMA16(aHi[0], bHi, acc[0][nf]);
            acc[1][nf] = MFMA16(aHi[1], bHi, acc[1][nf]);
            acc[2][nf] = MFMA16(aHi[2], bHi, acc[2][nf]);
            acc[3][nf] = MFMA16(aHi[3], bHi, acc[3][nf]);
            acc[0][nf] = MFMA16(aHi[0], bLo, acc[0][nf]);
            acc[1][nf] = MFMA16(aHi[1], bLo, acc[1][nf]);
            acc[2][nf] = MFMA16(aHi[2], bLo, acc[2][nf]);
            acc[3][nf] = MFMA16(aHi[3], bLo, acc[3][nf]);
            acc[0][nf] = MFMA16(aLo[0], bHi, acc[0][nf]);
            acc[1][nf] = MFMA16(aLo[1], bHi, acc[1][nf]);
            acc[2][nf] = MFMA16(aLo[2], bHi, acc[2][nf]);
            acc[3][nf] = MFMA16(aLo[3], bHi, acc[3][nf]);
            __builtin_amdgcn_s_setprio(0);
        }

        // issue chunk i+2 into the slot being read now? No -- ring2: issue i+1 happened
        // last iteration; here issue chunk i+2 is impossible. Issue next (i+2 distance-1
        // pattern): slot sl is freed at the upcoming barrier; chunk i+2 goes there NEXT iter.
        __builtin_amdgcn_sched_barrier(0);
        if (i + 2 < nsteps) {
            // chunk i+1 (issued last iter) must be fully landed before next step reads it;
            // our own chunk i+2 not yet issued, so a full drain here only waits chunk i+1.
            asm volatile("s_waitcnt vmcnt(0)" ::: "memory");
            __builtin_amdgcn_s_barrier();
            __builtin_amdgcn_sched_barrier(0);
            issue(i + 2, sl);   // into just-freed slot; lands during step i+1
        } else {
            asm volatile("s_waitcnt vmcnt(0)" ::: "memory");
            __builtin_amdgcn_s_barrier();
            __builtin_amdgcn_sched_barrier(0);
        }
    }

    // norm partials: wave (wm,wn) converted A rows [wm*64,+64) (dup x2 over wn) and
    // B rows [wn*64,+64) (dup x2 over wm); lanes {fr, fr+16, fr+32, fr+48} hold k-slices.
#pragma unroll
    for (int mf = 0; mf < 4; ++mf) {
        float s = sA[mf];
        s += __shfl_xor(s, 16);
        s += __shfl_xor(s, 32);
        if (jt == 0 && wn == 0 && lane < 16)
            x2p[(ks * B_ + b) * C_ + it * 128 + wm * 64 + mf * 16 + lane] = s;
    }
#pragma unroll
    for (int nf = 0; nf < 4; ++nf) {
        float s = sB[nf];
        s += __shfl_xor(s, 16);
        s += __shfl_xor(s, 32);
        if (it == 0 && wm == 0 && lane < 16)
            y2p[(ks * B_ + b) * C_ + jt * 128 + wn * 64 + nf * 16 + lane] = s;
    }

    // write G partial; C-layout: col = lane&15, row = (lane>>4)*4 + r
    size_t gbase = ((size_t)(ks * B_ + b) * C_ + it * 128) * C_ + jt * 128;
#pragma unroll
    for (int mf = 0; mf < 4; ++mf)
#pragma unroll
        for (int nf = 0; nf < 4; ++nf) {
            int rr = wm * 64 + mf * 16 + (lane >> 4) * 4;
            int cc = wn * 64 + nf * 16 + (lane & 15);
#pragma unroll
            for (int r = 0; r < 4; ++r)
                Gp[gbase + (size_t)(rr + r) * C_ + cc] = acc[mf][nf][r];
        }
}

// ---------------- kernel 2: reduce split-K, d2 = x2+y2-2G, argmin over j (tie -> smaller j) ----------------
__global__ __launch_bounds__(256) void argmin_kernel(const float* __restrict__ Gp,
                                                     const float* __restrict__ x2p,
                                                     const float* __restrict__ y2p,
                                                     float* __restrict__ minval,
                                                     int* __restrict__ minidx,
                                                     int KS) {
    int bi = blockIdx.x;           // b*C + i
    int b = bi >> 8;
    int i = bi & 255;
    int j = threadIdx.x;           // 0..255 == C

    float g = 0.f, sx = 0.f, sy = 0.f;
    for (int ks = 0; ks < KS; ++ks) {
        g  += Gp[((size_t)(ks * B_ + b) * C_ + i) * C_ + j];
        sx += x2p[(ks * B_ + b) * C_ + i];
        sy += y2p[(ks * B_ + b) * C_ + j];
    }

    float v = sx + sy - 2.f * g;
    int idx = j;
#pragma unroll
    for (int off = 32; off > 0; off >>= 1) {
        float v2 = __shfl_down(v, off);
        int i2 = __shfl_down(idx, off);
        if (v2 < v || (v2 == v && i2 < idx)) { v = v2; idx = i2; }
    }
    __shared__ float wv[4];
    __shared__ int wi[4];
    int lane = threadIdx.x & 63, wid = threadIdx.x >> 6;
    if (lane == 0) { wv[wid] = v; wi[wid] = idx; }
    __syncthreads();
    if (threadIdx.x == 0) {
        for (int w = 1; w < 4; ++w)
            if (wv[w] < v || (wv[w] == v && wi[w] < idx)) { v = wv[w]; idx = wi[w]; }
        minval[bi] = v;
        minidx[bi] = idx;
    }
}

// ---------------- kernel 3: per-batch stable top-128 selection + compaction ----------------
__global__ __launch_bounds__(256) void select_kernel(const float* __restrict__ minval,
                                                     const int* __restrict__ minidx,
                                                     int* __restrict__ nn) {
    int b = blockIdx.x;
    int i = threadIdx.x;           // channel
    __shared__ float vals[C_];
    __shared__ int wcnt[4];

    float v = minval[b * C_ + i];
    vals[i] = v;
    __syncthreads();

    int rank = 0;
    for (int tt = 0; tt < C_; ++tt) {
        float u = vals[tt];
        rank += (u < v) || (u == v && tt < i);
    }
    bool flag = rank < NM_;

    unsigned long long m = __ballot(flag);
    int lane = i & 63, wid = i >> 6;
    if (lane == 0) wcnt[wid] = (int)__popcll(m);
    __syncthreads();
    int off = 0;
    for (int w = 0; w < wid; ++w) off += wcnt[w];
    int pos = off + (int)__popcll(m & ((1ULL << lane) - 1ULL));
    if (flag) nn[b * NM_ + pos] = minidx[b * C_ + i];
}

// ---------------- kernel 4: gather selected Ym rows ----------------
__global__ __launch_bounds__(256) void gather_kernel(const float* __restrict__ Y,
                                                     const int* __restrict__ nn,
                                                     float* __restrict__ out) {
    int blk = blockIdx.x;
    int b = blk >> 7;
    int m = blk & 127;
    int src = nn[b * NM_ + m];
    const float4* s = (const float4*)(Y + ((size_t)b * C_ + src) * N_);
    float4* d = (float4*)(out + ((size_t)b * NM_ + m) * N_);
    for (int tt = threadIdx.x; tt < N_ / 4; tt += 256) d[tt] = s[tt];
}

extern "C" void kernel_launch(void* const* d_in, const int* in_sizes, int n_in,
                              void* d_out, int out_size, void* d_ws, size_t ws_size,
                              hipStream_t stream) {
    const float* X = (const float*)d_in[0];
    const float* Y = (const float*)d_in[1];
    float* out = (float*)d_out;

    // choose split-K factor by available workspace (exact need per KS)
    size_t favail = ws_size / 4;
    int KS = 1;
    while (KS < 16) {
        int KS2 = KS * 2;
        size_t need = (size_t)KS2 * B_ * C_ * C_          // Gp
                    + (size_t)KS2 * 2 * B_ * C_           // x2p, y2p
                    + 2 * B_ * C_ + B_ * NM_;             // minval/minidx/nn
        if (need > favail) break;
        KS = KS2;
    }
    int Kchunk = N_ / KS;

    float* minval = (float*)d_ws;
    int* minidx = (int*)(minval + B_ * C_);
    int* nn = minidx + B_ * C_;
    float* x2p = (float*)(nn + B_ * NM_);
    float* y2p = x2p + (size_t)KS * B_ * C_;
    float* Gp = y2p + (size_t)KS * B_ * C_;

    hipLaunchKernelGGL(gemm_f16_kernel, dim3(KS * 32), dim3(256), 0, stream, X, Y, Gp, x2p, y2p, Kchunk);
    hipLaunchKernelGGL(argmin_kernel, dim3(B_ * C_), dim3(256), 0, stream, Gp, x2p, y2p, minval, minidx, KS);
    hipLaunchKernelGGL(select_kernel, dim3(B_), dim3(256), 0, stream, minval, minidx, nn);
    hipLaunchKernelGGL(gather_kernel, dim3(B_ * NM_), dim3(256), 0, stream, Y, nn, out);
}